// Round 6
// baseline (543.410 us; speedup 1.0000x reference)
//
#include <hip/hip_runtime.h>

// CropRandomizer.forward_in with pos_enc=True, specialized to:
//   B=64, C=3, H=W=240, NUM_CROPS=8, CROP=216x216, Cp=5
// Output: [512, 5, 216, 216] fp32 = 477.8 MB (compulsory writes).
// Input: 44.2 MB, reused 8x -> should live in L2/L3.
//
// Structure: one workgroup per output plane (crop n, channel c).
//  - h0/w0 are block-uniform -> scalar loads, no per-element index loads.
//  - channel branch is block-uniform -> zero divergence.
//  - inner loop: flat t over 11664 float4, one magic-div by 54 per element.
//  - nontemporal stores (clang ext_vector f32x4 — HIP float4 is a class and
//    is rejected by __builtin_nontemporal_store): keep the 478 MB output
//    stream out of L2 so the source images stay resident for reuse.

#define CROP_HW   216
#define N_CROPS   8
#define IMG_C     3
#define IMG_H     240
#define IMG_W     240
#define CP        5

#define ROW4      (CROP_HW / 4)          // 54 float4 per row
#define PLANE4    (CROP_HW * ROW4)       // 11664 float4 per plane
#define CROP4     (CP * PLANE4)          // 58320 float4 per crop

typedef float f32x4 __attribute__((ext_vector_type(4)));

__global__ __launch_bounds__(256) void crop_pos_kernel(
    const float* __restrict__ images,
    const int*   __restrict__ ch,
    const int*   __restrict__ cw,
    f32x4*       __restrict__ out)
{
    const float inv = 1.0f / 240.0f;

    // blockIdx.x in [0, 512*5): blk = n*5 + c
    unsigned int blk = blockIdx.x;
    unsigned int n   = blk / CP;
    unsigned int c   = blk - n * CP;
    unsigned int b   = n >> 3;           // image index
    unsigned int cr  = n & 7;            // crop index within image

    int h0 = ch[b * N_CROPS + cr];       // block-uniform -> scalar load
    int w0 = cw[b * N_CROPS + cr];

    f32x4* outp = out + (size_t)n * CROP4 + (size_t)c * PLANE4;

    if (c < IMG_C) {
        const float* src0 = images
            + (((size_t)(b * IMG_C + c) * IMG_H) + (unsigned)h0) * IMG_W
            + (unsigned)w0;
        for (unsigned int t = threadIdx.x; t < PLANE4; t += 256) {
            unsigned int i  = t / ROW4;              // magic mul
            unsigned int j  = (t - i * ROW4) * 4;
            const float* s  = src0 + i * IMG_W + j;
            f32x4 v;
            v.x = s[0]; v.y = s[1]; v.z = s[2]; v.w = s[3];
            __builtin_nontemporal_store(v, &outp[t]);
        }
    } else if (c == 3) {
        // yy channel: (h0 + i) / H, constant across each row
        for (unsigned int t = threadIdx.x; t < PLANE4; t += 256) {
            unsigned int i = t / ROW4;
            float val = (float)(h0 + (int)i) * inv;
            f32x4 v; v.x = val; v.y = val; v.z = val; v.w = val;
            __builtin_nontemporal_store(v, &outp[t]);
        }
    } else {
        // xx channel: (w0 + j + k) / W
        for (unsigned int t = threadIdx.x; t < PLANE4; t += 256) {
            unsigned int i = t / ROW4;
            unsigned int j = (t - i * ROW4) * 4;
            float base = (float)(w0 + (int)j) * inv;
            f32x4 v;
            v.x = base;
            v.y = base + inv;
            v.z = base + 2.0f * inv;
            v.w = base + 3.0f * inv;
            __builtin_nontemporal_store(v, &outp[t]);
        }
    }
}

extern "C" void kernel_launch(void* const* d_in, const int* in_sizes, int n_in,
                              void* d_out, int out_size, void* d_ws, size_t ws_size,
                              hipStream_t stream) {
    const float* images = (const float*)d_in[0];
    const int*   ch     = (const int*)d_in[1];
    const int*   cw     = (const int*)d_in[2];
    f32x4*       out    = (f32x4*)d_out;

    dim3 block(256);
    dim3 grid(512 * CP);   // one block per (crop, channel) plane
    crop_pos_kernel<<<grid, block, 0, stream>>>(images, ch, cw, out);
}